// Round 11
// baseline (614.070 us; speedup 1.0000x reference)
//
#include <hip/hip_runtime.h>
#include <hip/hip_bf16.h>

#define N_NODES 8192
#define CAP 128
#define XSTR 200   // bf16 elems per LDS x-row
#define FFSTR 193  // f32 elems per LDS feat-row
#define NBLK 512
#define SUPSZ (N_NODES * 64)   // ushorts per per-layer sup buffer (1 MB, bf16)

typedef short s16x8 __attribute__((ext_vector_type(8)));
typedef float f32x4 __attribute__((ext_vector_type(4)));
typedef unsigned short u16x8 __attribute__((ext_vector_type(8)));

// ---------------------------------------------------------------------------
// sc1 (agent-scope) stores: producer data lands at the coherence point before
// the barrier; consumers use NORMAL cached loads (write-once buffers).
// ---------------------------------------------------------------------------
__device__ __forceinline__ void cstoref(float* p, float v) {
    __hip_atomic_store(p, v, __ATOMIC_RELAXED, __HIP_MEMORY_SCOPE_AGENT);
}
__device__ __forceinline__ void cstoreh(unsigned short* p, unsigned short v) {
    __hip_atomic_store(p, v, __ATOMIC_RELAXED, __HIP_MEMORY_SCOPE_AGENT);
}
__device__ __forceinline__ void cstorei(int* p, int v) {
    __hip_atomic_store(p, v, __ATOMIC_RELAXED, __HIP_MEMORY_SCOPE_AGENT);
}
__device__ __forceinline__ int cloadi(const int* p) {
    return __hip_atomic_load(p, __ATOMIC_RELAXED, __HIP_MEMORY_SCOPE_AGENT);
}
__device__ __forceinline__ float b2f(unsigned short u) {
    union { unsigned int i; float f; } c; c.i = ((unsigned int)u) << 16; return c.f;
}

// ---------------------------------------------------------------------------
// Symmetric all-poll grid barrier v4. Lessons: R8/R9 hierarchical counters =
// serialized RMW chains (~8us/phase); R10 flag+aggregator = work-burdened
// block 0 on the critical path every phase (+2.2us vs R9). Here: NO RMWs,
// NO aggregator, NO go-flag hop.
//   arrive: vmcnt-drain, syncthreads, leader sc1-STORES phase to its OWN
//           flag line (512 independent lines, fully parallel).
//   wait:   EVERY block's wave 0 polls all 512 flags itself: 8 flags/lane,
//           one vmem round (~0.35us), shfl min-reduce. One-hop detection.
// Poll traffic ~1MB/round grid-wide at L3 read BW -- negligible.
// Monotonic phases; memset once per launch.
// ---------------------------------------------------------------------------
__device__ __forceinline__ void gbar_arrive(int* bar, int phase) {
    asm volatile("s_waitcnt vmcnt(0)" ::: "memory");
    __syncthreads();
    if (threadIdx.x == 0)
        cstorei(bar + blockIdx.x * 32, phase);
}
__device__ __forceinline__ void gbar_wait(int* bar, int phase) {
    if (threadIdx.x < 64) {
        const int lane = threadIdx.x;
        int rounds = 0;
        for (;;) {
            int mn = 0x7fffffff;
#pragma unroll
            for (int j = 0; j < 8; ++j)
                mn = min(mn, cloadi(bar + (lane * 8 + j) * 32));
#pragma unroll
            for (int off = 32; off > 0; off >>= 1)
                mn = min(mn, __shfl_xor(mn, off));
            if (mn >= phase) break;
            if (rounds < 4) __builtin_amdgcn_s_sleep(1);
            else            __builtin_amdgcn_s_sleep(4);
            if (++rounds > (1 << 20)) break;    // failsafe: no hang
        }
    }
    __syncthreads();
}
__device__ __forceinline__ void gbar(int* bar, int phase) {
    gbar_arrive(bar, phase);
    gbar_wait(bar, phase);
}

// ---------------------------------------------------------------------------
// Async global->LDS 16B DMA. LDS dest = wave-uniform base + lane*16;
// global src per-lane. Linear both sides (rule #21).
// ---------------------------------------------------------------------------
__device__ __forceinline__ void gload_lds16(unsigned int* lds, const unsigned int* src) {
    __builtin_amdgcn_global_load_lds(
        (const __attribute__((address_space(1))) void*)src,
        (__attribute__((address_space(3))) void*)lds, 16, 0, 0);
}

// ---------------------------------------------------------------------------
// Weight transform slice (cooperative, inlined). idx < 61440. sc1 stores.
// ---------------------------------------------------------------------------
__device__ __forceinline__ void transform_slice(int idx,
    const float* __restrict__ W1, const float* __restrict__ Wm,
    unsigned short* __restrict__ Wt1, unsigned short* __restrict__ WtM)
{
    if (idx >= 6144 + 55296) return;
    const float* src; unsigned short* dst; int KT, t, c, lane;
    if (idx < 6144) {
        KT = 8; src = W1; dst = Wt1;
        t = idx / 512; c = (idx >> 6) & 7; lane = idx & 63;
    } else {
        int r = idx - 6144;
        int mat = r / 4608;
        int rem = r % 4608;
        KT = 6; src = Wm + (size_t)mat * 36864; dst = WtM + (size_t)mat * 36864;
        t = rem / 384; c = (rem >> 6) % 6; lane = rem & 63;
    }
    int n = t * 16 + (lane & 15);
    int k0 = c * 32 + ((lane >> 4) << 3);
    union { u16x8 v; unsigned long long q[2]; } u;
#pragma unroll
    for (int j = 0; j < 8; ++j)
        u.v[j] = __bfloat16_as_ushort(__float2bfloat16(src[(size_t)(k0 + j) * 192 + n]));
    unsigned long long* dp =
        (unsigned long long*)(dst + ((size_t)(t * KT + c) * 64 + lane) * 8);
    __hip_atomic_store(dp,     u.q[0], __ATOMIC_RELAXED, __HIP_MEMORY_SCOPE_AGENT);
    __hip_atomic_store(dp + 1, u.q[1], __ATOMIC_RELAXED, __HIP_MEMORY_SCOPE_AGENT);
}

// ---------------------------------------------------------------------------
// A-fragment loaders. Layout: A[m = lane&15][k = quad*8 + c*32 + j].
// ---------------------------------------------------------------------------
template<int KT>
__device__ __forceinline__ void load_a(s16x8* a, const unsigned short* xs,
                                       int lane, int quad) {
    const short* xr = reinterpret_cast<const short*>(xs) + (lane & 15) * XSTR + quad * 8;
#pragma unroll
    for (int c = 0; c < KT; ++c) a[c] = *reinterpret_cast<const s16x8*>(xr + c * 32);
}

__device__ __forceinline__ void load_a_feat(s16x8* a, const float* __restrict__ features,
                                            int m0, int lane, int quad) {
    const float* fr = features + (((size_t)(m0 + (lane & 15))) << 8) + quad * 8;
#pragma unroll
    for (int c = 0; c < 8; ++c) {
        float4 f0 = *reinterpret_cast<const float4*>(fr + c * 32);
        float4 f1 = *reinterpret_cast<const float4*>(fr + c * 32 + 4);
        s16x8 v;
        v[0] = (short)__bfloat16_as_ushort(__float2bfloat16(f0.x));
        v[1] = (short)__bfloat16_as_ushort(__float2bfloat16(f0.y));
        v[2] = (short)__bfloat16_as_ushort(__float2bfloat16(f0.z));
        v[3] = (short)__bfloat16_as_ushort(__float2bfloat16(f0.w));
        v[4] = (short)__bfloat16_as_ushort(__float2bfloat16(f1.x));
        v[5] = (short)__bfloat16_as_ushort(__float2bfloat16(f1.y));
        v[6] = (short)__bfloat16_as_ushort(__float2bfloat16(f1.z));
        v[7] = (short)__bfloat16_as_ushort(__float2bfloat16(f1.w));
        a[c] = v;
    }
}

// ---------------------------------------------------------------------------
// Matmul phase. n<64 -> bf16 sup (sc1); n>=64 -> epilogue into LDS.
// EP: 0 x=relu; 1 feat=(featG+relu)/2; 2 feat=(feat+relu)/2; 3 EP2+outFeat.
// ---------------------------------------------------------------------------
template<int KT, int EP>
__device__ __forceinline__ void mm_core(
    const s16x8* a, const unsigned short* __restrict__ Wt,
    const float* __restrict__ bias, unsigned short* __restrict__ supW,
    unsigned short* xdst, float* featL,
    const float* __restrict__ featG, float* __restrict__ outFeat,
    int m0, int lane, int wave, int quad)
{
    f32x4 acc[3] = {};
    const short* wb = reinterpret_cast<const short*>(Wt);
#pragma unroll
    for (int tt = 0; tt < 3; ++tt) {
        const int t = wave * 3 + tt;
        const short* wp = wb + ((size_t)t * KT * 64 + lane) * 8;
#pragma unroll
        for (int c = 0; c < KT; ++c) {
            s16x8 b = *reinterpret_cast<const s16x8*>(wp + (size_t)c * 512);
            acc[tt] = __builtin_amdgcn_mfma_f32_16x16x32_bf16(a[c], b, acc[tt], 0, 0, 0);
        }
    }
#pragma unroll
    for (int tt = 0; tt < 3; ++tt) {
        const int n = (wave * 3 + tt) * 16 + (lane & 15);
#pragma unroll
        for (int r = 0; r < 4; ++r) {
            const int m = quad * 4 + r;
            float v = acc[tt][r];
            if (n < 64) {
                cstoreh(&supW[(((size_t)(m0 + m)) << 6) + n],
                        __bfloat16_as_ushort(__float2bfloat16(v)));
            } else {
                v += bias[n];
                float x = fmaxf(v, 0.f);
                if constexpr (EP == 0) {
                    xdst[m * XSTR + n] = __bfloat16_as_ushort(__float2bfloat16(x));
                } else if constexpr (EP == 1) {
                    float f = (featG[(size_t)(m0 + m) * 256 + n] + x) * 0.5f;
                    featL[m * FFSTR + n] = f;
                    xdst[m * XSTR + n] = __bfloat16_as_ushort(__float2bfloat16(f));
                } else if constexpr (EP == 2) {
                    float f = (featL[m * FFSTR + n] + x) * 0.5f;
                    featL[m * FFSTR + n] = f;
                    xdst[m * XSTR + n] = __bfloat16_as_ushort(__float2bfloat16(f));
                } else {
                    float f = (featL[m * FFSTR + n] + x) * 0.5f;
                    featL[m * FFSTR + n] = f;
                    outFeat[(size_t)(m0 + m) * 192 + n] = f;
                }
            }
        }
    }
}

// ---------------------------------------------------------------------------
// Aggregation: wave's 4 rows interleaved, k-step 8 -> 32 cached bf16 gather
// loads in flight. Tails masked; &8191 keeps speculative loads in-bounds.
// ---------------------------------------------------------------------------
template<int EP>
__device__ __forceinline__ void agg_phase(
    const unsigned short* __restrict__ supR,
    const int* colsL, const int* cntL,
    const float* __restrict__ bias, unsigned short* xdst,
    float* featL, const float* __restrict__ featG,
    float* __restrict__ outFeat,
    int m0, int lane, int wave)
{
    const int base = wave * 4;
    int na[4];
#pragma unroll
    for (int rr = 0; rr < 4; ++rr) na[rr] = cntL[base + rr];
    int nmax = max(max(na[0], na[1]), max(na[2], na[3]));
    float s[4] = {0.f, 0.f, 0.f, 0.f};
    for (int k = 0; k < nmax; k += 8) {
        float v[32];
#pragma unroll
        for (int rr = 0; rr < 4; ++rr) {
            int4 c0 = *reinterpret_cast<const int4*>(colsL + (base + rr) * CAP + k);
            int4 c1 = *reinterpret_cast<const int4*>(colsL + (base + rr) * CAP + k + 4);
            v[rr * 8 + 0] = b2f(supR[((size_t)(c0.x & 8191) << 6) + lane]);
            v[rr * 8 + 1] = b2f(supR[((size_t)(c0.y & 8191) << 6) + lane]);
            v[rr * 8 + 2] = b2f(supR[((size_t)(c0.z & 8191) << 6) + lane]);
            v[rr * 8 + 3] = b2f(supR[((size_t)(c0.w & 8191) << 6) + lane]);
            v[rr * 8 + 4] = b2f(supR[((size_t)(c1.x & 8191) << 6) + lane]);
            v[rr * 8 + 5] = b2f(supR[((size_t)(c1.y & 8191) << 6) + lane]);
            v[rr * 8 + 6] = b2f(supR[((size_t)(c1.z & 8191) << 6) + lane]);
            v[rr * 8 + 7] = b2f(supR[((size_t)(c1.w & 8191) << 6) + lane]);
        }
#pragma unroll
        for (int rr = 0; rr < 4; ++rr) {
#pragma unroll
            for (int j = 0; j < 8; ++j)
                s[rr] += (k + j < na[rr]) ? v[rr * 8 + j] : 0.f;
        }
    }
#pragma unroll
    for (int rr = 0; rr < 4; ++rr) {
        const int lrow = base + rr;
        const int row = m0 + lrow;
        float vv = s[rr] * 0.03125f + bias[lane];
        float x = fmaxf(vv, 0.f);
        if constexpr (EP == 0) {
            xdst[lrow * XSTR + lane] = __bfloat16_as_ushort(__float2bfloat16(x));
        } else if constexpr (EP == 1) {
            float f = (featG[(size_t)row * 256 + lane] + x) * 0.5f;
            featL[lrow * FFSTR + lane] = f;
            xdst[lrow * XSTR + lane] = __bfloat16_as_ushort(__float2bfloat16(f));
        } else if constexpr (EP == 2) {
            float f = (featL[lrow * FFSTR + lane] + x) * 0.5f;
            featL[lrow * FFSTR + lane] = f;
            xdst[lrow * XSTR + lane] = __bfloat16_as_ushort(__float2bfloat16(f));
        } else {
            float f = (featL[lrow * FFSTR + lane] + x) * 0.5f;
            featL[lrow * FFSTR + lane] = f;
            outFeat[(size_t)row * 192 + lane] = f;
        }
    }
}

// ---------------------------------------------------------------------------
// Persistent fused kernel. ph1: cooperative weight transform; pipelined adj
// scan (DMA-staged) builds the LDS CSR. Then per layer: mm -> gbar -> agg ->
// sync. Write-once bf16 sup per layer. LDS ~66 KB -> 2 blocks/CU.
// ---------------------------------------------------------------------------
__global__ __launch_bounds__(256, 2) void fused_gcn(
    const float* __restrict__ features,
    const unsigned int* __restrict__ adj,
    const float* __restrict__ W1, const float* __restrict__ Wm,
    unsigned short* __restrict__ Wt1, unsigned short* __restrict__ WtM,
    const float* __restrict__ b1, const float* __restrict__ bm,
    const float* __restrict__ Wout, const float* __restrict__ bout,
    unsigned short* __restrict__ supBase, float* __restrict__ sup3,
    float* __restrict__ out, float* __restrict__ outFeat,
    int* __restrict__ bar)
{
    __shared__ unsigned short xsA[16 * XSTR];
    __shared__ unsigned short xsB[16 * XSTR];
    __shared__ float featL[16 * FFSTR];
    __shared__ int colsL[16 * CAP];
    __shared__ int cntL[16];
    __shared__ __align__(16) unsigned int adjL2[2][4096];   // 2 x 16 KB halves

    const int tid = threadIdx.x;
    const int lane = tid & 63;
    const int wave = tid >> 6;
    const int quad = lane >> 4;
    const int m0 = blockIdx.x * 16;
    int ph = 0;

    // ---- ph1: cooperative weight transform (sc1 stores), arrive
    transform_slice(blockIdx.x * 256 + tid, W1, Wm, Wt1, WtM);
    gbar_arrive(bar, ++ph);

    // ---- pipelined adj scan -> LDS CSR (fills ph1's wait; ~BW-bound)
    if (tid < 16) cntL[tid] = 0;
    {
        auto stage = [&](int hr) {
            const unsigned int* src = adj + ((size_t)(m0 + (hr >> 1)) << 13)
                                          + ((hr & 1) << 12);
            unsigned int* dstb = adjL2[hr & 1];
#pragma unroll
            for (int i = 0; i < 4; ++i) {
                int off = (wave * 4 + i) * 256;          // uints, wave-uniform
                gload_lds16(dstb + off, src + off + lane * 4);
            }
        };
        stage(0);
        for (int hr = 0; hr < 32; ++hr) {
            if (hr < 31) stage(hr + 1);
            __builtin_amdgcn_sched_barrier(0);
            if (hr < 31) asm volatile("s_waitcnt vmcnt(4)" ::: "memory");
            else         asm volatile("s_waitcnt vmcnt(0)" ::: "memory");
            __builtin_amdgcn_sched_barrier(0);
            __syncthreads();
            const int r = hr >> 1;
            const unsigned int* buf = adjL2[hr & 1];
#pragma unroll
            for (int j = 0; j < 4; ++j) {
                int chunk = tid + j * 256;
                uint4 v = *reinterpret_cast<const uint4*>(buf + chunk * 4);
                if ((v.x | v.y | v.z | v.w) == 0u) continue;
                int e0 = ((hr & 1) << 12) + (chunk << 2);
                int loc[4]; int k = 0;
                if (v.x) loc[k++] = e0;
                if (v.y) loc[k++] = e0 + 1;
                if (v.z) loc[k++] = e0 + 2;
                if (v.w) loc[k++] = e0 + 3;
                int pos = atomicAdd(&cntL[r], k);
                for (int jj = 0; jj < k; ++jj)
                    if (pos + jj < CAP) colsL[r * CAP + pos + jj] = loc[jj];
            }
            __syncthreads();
        }
    }
    if (tid < 16) cntL[tid] = cntL[tid] > CAP ? CAP : cntL[tid];
    gbar_wait(bar, ph);                    // weights ready everywhere

    // ---- gc1: KT=8, A from global f32 features, EP0 -> xsA, sup[0]
    {
        s16x8 a[8];
        load_a_feat(a, features, m0, lane, quad);
        mm_core<8, 0>(a, Wt1, b1, supBase, xsA, featL, features, outFeat, m0, lane, wave, quad);
    }
    gbar(bar, ++ph);
    agg_phase<0>(supBase, colsL, cntL, b1, xsA, featL, features, outFeat, m0, lane, wave);
    __syncthreads();

    // ---- gc2 (W_mid[0]): EP1, reads xsA -> writes xsB, sup[1]
    {
        s16x8 a[6];
        load_a<6>(a, xsA, lane, quad);
        mm_core<6, 1>(a, WtM, bm, supBase + SUPSZ, xsB, featL, features, outFeat, m0, lane, wave, quad);
    }
    gbar(bar, ++ph);
    agg_phase<1>(supBase + SUPSZ, colsL, cntL, bm, xsB, featL, features, outFeat, m0, lane, wave);
    __syncthreads();

    // ---- gc3..gc12: 5 residual pairs, W_mid[1+2p] (EP0) then W_mid[2+2p] (EP2)
    for (int p = 0; p < 5; ++p) {
        unsigned short* supA = supBase + (size_t)(2 + 2 * p) * SUPSZ;
        const unsigned short* WtA = WtM + (size_t)(1 + 2 * p) * 36864;
        const float* bA = bm + (size_t)(1 + 2 * p) * 192;
        {
            s16x8 a[6];
            load_a<6>(a, xsB, lane, quad);
            mm_core<6, 0>(a, WtA, bA, supA, xsA, featL, features, outFeat, m0, lane, wave, quad);
        }
        gbar(bar, ++ph);
        agg_phase<0>(supA, colsL, cntL, bA, xsA, featL, features, outFeat, m0, lane, wave);
        __syncthreads();

        unsigned short* supB = supA + SUPSZ;
        const unsigned short* WtB = WtA + 36864;
        const float* bB = bA + 192;
        {
            s16x8 a[6];
            load_a<6>(a, xsA, lane, quad);
            mm_core<6, 2>(a, WtB, bB, supB, xsB, featL, features, outFeat, m0, lane, wave, quad);
        }
        gbar(bar, ++ph);
        agg_phase<2>(supB, colsL, cntL, bB, xsB, featL, features, outFeat, m0, lane, wave);
        __syncthreads();
    }

    // ---- gc13 (W_mid[11]): EP3, reads xsB; feat -> outFeat (f32), sup[12]
    {
        unsigned short* sup13 = supBase + (size_t)12 * SUPSZ;
        const unsigned short* Wt13 = WtM + (size_t)11 * 36864;
        const float* b13 = bm + (size_t)11 * 192;
        {
            s16x8 a[6];
            load_a<6>(a, xsB, lane, quad);
            mm_core<6, 3>(a, Wt13, b13, sup13, xsA, featL, features, outFeat, m0, lane, wave, quad);
        }
        gbar(bar, ++ph);
        agg_phase<3>(sup13, colsL, cntL, b13, xsA, featL, features, outFeat, m0, lane, wave);
        __syncthreads();
    }

    // ---- gc14 matmul: sup3[row] = feat[row] . Wout (K=192, N=3)
#pragma unroll
    for (int rr = 0; rr < 4; ++rr) {
        const int lrow = wave * 4 + rr;
        float s0 = 0.f, s1 = 0.f, s2 = 0.f;
#pragma unroll
        for (int pp = 0; pp < 3; ++pp) {
            int kk = pp * 64 + lane;
            float f = featL[lrow * FFSTR + kk];
            s0 += f * Wout[kk * 3 + 0];
            s1 += f * Wout[kk * 3 + 1];
            s2 += f * Wout[kk * 3 + 2];
        }
#pragma unroll
        for (int off = 32; off > 0; off >>= 1) {
            s0 += __shfl_down(s0, off);
            s1 += __shfl_down(s1, off);
            s2 += __shfl_down(s2, off);
        }
        if (lane == 0) {
            float* sp = sup3 + (((size_t)(m0 + lrow)) << 2);
            cstoref(sp + 0, s0);
            cstoref(sp + 1, s1);
            cstoref(sp + 2, s2);
        }
    }
    gbar(bar, ++ph);

    // ---- gc14 aggregation: side_len = 2; 16 threads per row (cached loads)
    {
        const int lrow = tid >> 4;
        const int row = m0 + lrow;
        const int sub = tid & 15;
        int n = cntL[lrow];
        const int* cl = colsL + lrow * CAP;
        float s0 = 0.f, s1 = 0.f;
        for (int k = sub; k < n; k += 16) {
            int j = cl[k];
            s0 += sup3[((size_t)j << 2) + 0];
            s1 += sup3[((size_t)j << 2) + 1];
        }
#pragma unroll
        for (int off = 8; off > 0; off >>= 1) {
            s0 += __shfl_down(s0, off, 16);
            s1 += __shfl_down(s1, off, 16);
        }
        if (sub == 0) {
            float* op = out + (size_t)row * 3;
            op[0] = s0 * 0.03125f + bout[0];
            op[1] = s1 * 0.03125f + bout[1];
            op[2] = sup3[((size_t)row << 2) + 2] + bout[2];
        }
    }
}

extern "C" void kernel_launch(void* const* d_in, const int* in_sizes, int n_in,
                              void* d_out, int out_size, void* d_ws, size_t ws_size,
                              hipStream_t stream) {
    const float* features = (const float*)d_in[0];
    const unsigned int* adj = (const unsigned int*)d_in[1];
    const float* W1 = (const float*)d_in[2];
    const float* b1 = (const float*)d_in[3];
    const float* Wm = (const float*)d_in[4];
    const float* bm = (const float*)d_in[5];
    const float* Wo = (const float*)d_in[6];
    const float* bo = (const float*)d_in[7];
    float* out = (float*)d_out;
    float* outFeat = out + (size_t)N_NODES * 3;

    char* w = (char*)d_ws;
    int* bar = (int*)(w);                                     // 64 KB flag lines
    unsigned short* supBase = (unsigned short*)(w + 131072);  // 13 x 1 MB -> 13,762,560
    float* sup3 = (float*)(w + 13762560);                     // 128 KB -> 13,893,632
    unsigned short* Wt1 = (unsigned short*)(w + 13893632);    // 96 KB -> 13,991,936
    unsigned short* WtM = (unsigned short*)(w + 13991936);    // 864 KB -> 14,876,672

    hipMemsetAsync(bar, 0, NBLK * 32 * sizeof(int) + 128, stream);

    fused_gcn<<<NBLK, 256, 0, stream>>>(features, adj, W1, Wm, Wt1, WtM, b1, bm,
                                        Wo, bo, supBase, sup3, out, outFeat, bar);

    (void)in_sizes; (void)n_in; (void)out_size; (void)ws_size;
}

// Round 12
// 549.439 us; speedup vs baseline: 1.1176x; 1.1176x over previous
//
#include <hip/hip_runtime.h>
#include <hip/hip_bf16.h>

#define N_NODES 8192
#define CAP 128
#define XSTR 200   // bf16 elems per LDS x-row
#define FFSTR 193  // f32 elems per LDS feat-row
#define NBLK 512
#define SUPSZ (N_NODES * 64)   // ushorts per per-layer sup buffer (1 MB, bf16)
#define LEAF_BASE 16384        // int index of leaf-done flags in bar[]

typedef short s16x8 __attribute__((ext_vector_type(8)));
typedef float f32x4 __attribute__((ext_vector_type(4)));
typedef unsigned short u16x8 __attribute__((ext_vector_type(8)));

// ---------------------------------------------------------------------------
// sc1 (agent-scope) stores: producer data lands at the coherence point before
// the barrier; consumers use NORMAL cached loads (write-once buffers).
// ---------------------------------------------------------------------------
__device__ __forceinline__ void cstoref(float* p, float v) {
    __hip_atomic_store(p, v, __ATOMIC_RELAXED, __HIP_MEMORY_SCOPE_AGENT);
}
__device__ __forceinline__ void cstoreh(unsigned short* p, unsigned short v) {
    __hip_atomic_store(p, v, __ATOMIC_RELAXED, __HIP_MEMORY_SCOPE_AGENT);
}
__device__ __forceinline__ void cstorei(int* p, int v) {
    __hip_atomic_store(p, v, __ATOMIC_RELAXED, __HIP_MEMORY_SCOPE_AGENT);
}
__device__ __forceinline__ int cloadi(const int* p) {
    return __hip_atomic_load(p, __ATOMIC_RELAXED, __HIP_MEMORY_SCOPE_AGENT);
}
__device__ __forceinline__ float b2f(unsigned short u) {
    union { unsigned int i; float f; } c; c.i = ((unsigned int)u) << 16; return c.f;
}

// ---------------------------------------------------------------------------
// Hierarchical FLAG barrier v5. Measured failure modes it avoids:
//  R9 counters: serialized RMW queues (16-deep leaf + 32-deep root, ~0.35us
//     coherence RMW each when blocks arrive together) -> ~8us/phase.
//  R10 single aggregator: detection gated on a full-work block (+2us).
//  R11 all-poll: 512 blk x 512 flags x 64B = 16MB/round poll traffic (+3us).
// Here: arrive = parallel sc1 STORE to own flag line (no queues).
// 32 leaf pollers (block 16i, polls right after its own arrival) publish
// leaf-done; everyone polls only the 32 leaf-done lines (~1MB/round).
// Monotonic phases; memset once per launch.
// ---------------------------------------------------------------------------
__device__ __forceinline__ void gbar_arrive(int* bar, int phase) {
    asm volatile("s_waitcnt vmcnt(0)" ::: "memory");
    __syncthreads();
    if (threadIdx.x == 0)
        cstorei(bar + blockIdx.x * 32, phase);
}
__device__ __forceinline__ void gbar_wait(int* bar, int phase) {
    const int tid = threadIdx.x;
    if (tid < 64) {
        if ((blockIdx.x & 15) == 0) {                 // leaf poller
            const int leaf = blockIdx.x >> 4;
            int rounds = 0;
            for (;;) {
                int v = (tid < 16) ? cloadi(bar + (leaf * 16 + tid) * 32)
                                   : 0x7fffffff;
#pragma unroll
                for (int off = 32; off > 0; off >>= 1)
                    v = min(v, __shfl_xor(v, off));
                if (v >= phase) break;
                __builtin_amdgcn_s_sleep(1);
                if (++rounds > (1 << 20)) break;      // failsafe: no hang
            }
            if (tid == 0) cstorei(bar + LEAF_BASE + leaf * 32, phase);
        }
        int rounds = 0;
        for (;;) {
            int v = (tid < 32) ? cloadi(bar + LEAF_BASE + tid * 32)
                               : 0x7fffffff;
#pragma unroll
            for (int off = 32; off > 0; off >>= 1)
                v = min(v, __shfl_xor(v, off));
            if (v >= phase) break;
            if (rounds < 8) __builtin_amdgcn_s_sleep(1);
            else            __builtin_amdgcn_s_sleep(4);
            if (++rounds > (1 << 20)) break;          // failsafe: no hang
        }
    }
    __syncthreads();
}

// ---------------------------------------------------------------------------
// Async global->LDS 16B DMA. LDS dest = wave-uniform base + lane*16;
// global src per-lane. Linear both sides (rule #21).
// ---------------------------------------------------------------------------
__device__ __forceinline__ void gload_lds16(unsigned int* lds, const unsigned int* src) {
    __builtin_amdgcn_global_load_lds(
        (const __attribute__((address_space(1))) void*)src,
        (__attribute__((address_space(3))) void*)lds, 16, 0, 0);
}

// ---------------------------------------------------------------------------
// Weight transform slice (cooperative, inlined). idx < 61440. sc1 stores.
// ---------------------------------------------------------------------------
__device__ __forceinline__ void transform_slice(int idx,
    const float* __restrict__ W1, const float* __restrict__ Wm,
    unsigned short* __restrict__ Wt1, unsigned short* __restrict__ WtM)
{
    if (idx >= 6144 + 55296) return;
    const float* src; unsigned short* dst; int KT, t, c, lane;
    if (idx < 6144) {
        KT = 8; src = W1; dst = Wt1;
        t = idx / 512; c = (idx >> 6) & 7; lane = idx & 63;
    } else {
        int r = idx - 6144;
        int mat = r / 4608;
        int rem = r % 4608;
        KT = 6; src = Wm + (size_t)mat * 36864; dst = WtM + (size_t)mat * 36864;
        t = rem / 384; c = (rem >> 6) % 6; lane = rem & 63;
    }
    int n = t * 16 + (lane & 15);
    int k0 = c * 32 + ((lane >> 4) << 3);
    union { u16x8 v; unsigned long long q[2]; } u;
#pragma unroll
    for (int j = 0; j < 8; ++j)
        u.v[j] = __bfloat16_as_ushort(__float2bfloat16(src[(size_t)(k0 + j) * 192 + n]));
    unsigned long long* dp =
        (unsigned long long*)(dst + ((size_t)(t * KT + c) * 64 + lane) * 8);
    __hip_atomic_store(dp,     u.q[0], __ATOMIC_RELAXED, __HIP_MEMORY_SCOPE_AGENT);
    __hip_atomic_store(dp + 1, u.q[1], __ATOMIC_RELAXED, __HIP_MEMORY_SCOPE_AGENT);
}

// ---------------------------------------------------------------------------
// gc1 A loader from f32 features. A[m=lane&15][k=quad*8 + c*32 + j].
// ---------------------------------------------------------------------------
__device__ __forceinline__ void load_a_feat(s16x8* a, const float* __restrict__ features,
                                            int m0, int lane, int quad) {
    const float* fr = features + (((size_t)(m0 + (lane & 15))) << 8) + quad * 8;
#pragma unroll
    for (int c = 0; c < 8; ++c) {
        float4 f0 = *reinterpret_cast<const float4*>(fr + c * 32);
        float4 f1 = *reinterpret_cast<const float4*>(fr + c * 32 + 4);
        s16x8 v;
        v[0] = (short)__bfloat16_as_ushort(__float2bfloat16(f0.x));
        v[1] = (short)__bfloat16_as_ushort(__float2bfloat16(f0.y));
        v[2] = (short)__bfloat16_as_ushort(__float2bfloat16(f0.z));
        v[3] = (short)__bfloat16_as_ushort(__float2bfloat16(f0.w));
        v[4] = (short)__bfloat16_as_ushort(__float2bfloat16(f1.x));
        v[5] = (short)__bfloat16_as_ushort(__float2bfloat16(f1.y));
        v[6] = (short)__bfloat16_as_ushort(__float2bfloat16(f1.z));
        v[7] = (short)__bfloat16_as_ushort(__float2bfloat16(f1.w));
        a[c] = v;
    }
}

// ---------------------------------------------------------------------------
// Partial MFMA accumulate over K-chunk range [C0,C1). Chunk c covers
// k in [c*32, c*32+32). c=0,1 need agg output (cols 0-63); c>=2 only need
// the pass-through cols -> usable BEFORE the barrier wait (overlap).
// ---------------------------------------------------------------------------
template<int KT, int C0, int C1>
__device__ __forceinline__ void mm_acc(f32x4* acc, const unsigned short* xs,
                                       const unsigned short* __restrict__ Wt,
                                       int lane, int wave, int quad) {
    const short* xr = reinterpret_cast<const short*>(xs) + (lane & 15) * XSTR + quad * 8;
    s16x8 a[C1 - C0];
#pragma unroll
    for (int c = C0; c < C1; ++c)
        a[c - C0] = *reinterpret_cast<const s16x8*>(xr + c * 32);
    const short* wb = reinterpret_cast<const short*>(Wt);
#pragma unroll
    for (int tt = 0; tt < 3; ++tt) {
        const int t = wave * 3 + tt;
        const short* wp = wb + ((size_t)t * KT * 64 + lane) * 8;
#pragma unroll
        for (int c = C0; c < C1; ++c) {
            s16x8 b = *reinterpret_cast<const s16x8*>(wp + (size_t)c * 512);
            acc[tt] = __builtin_amdgcn_mfma_f32_16x16x32_bf16(a[c - C0], b, acc[tt], 0, 0, 0);
        }
    }
}

// ---------------------------------------------------------------------------
// Epilogue: n<64 -> bf16 sup (sc1); n>=64 -> EP transform into LDS.
// EP: 0 x=relu; 1 feat=(featG+relu)/2; 2 feat=(feat+relu)/2; 3 EP2+outFeat.
// ---------------------------------------------------------------------------
template<int EP>
__device__ __forceinline__ void mm_epilogue(
    const f32x4* acc, const float* __restrict__ bias,
    unsigned short* __restrict__ supW, unsigned short* xdst, float* featL,
    const float* __restrict__ featG, float* __restrict__ outFeat,
    int m0, int lane, int wave, int quad)
{
#pragma unroll
    for (int tt = 0; tt < 3; ++tt) {
        const int n = (wave * 3 + tt) * 16 + (lane & 15);
#pragma unroll
        for (int r = 0; r < 4; ++r) {
            const int m = quad * 4 + r;
            float v = acc[tt][r];
            if (n < 64) {
                cstoreh(&supW[(((size_t)(m0 + m)) << 6) + n],
                        __bfloat16_as_ushort(__float2bfloat16(v)));
            } else {
                v += bias[n];
                float x = fmaxf(v, 0.f);
                if constexpr (EP == 0) {
                    xdst[m * XSTR + n] = __bfloat16_as_ushort(__float2bfloat16(x));
                } else if constexpr (EP == 1) {
                    float f = (featG[(size_t)(m0 + m) * 256 + n] + x) * 0.5f;
                    featL[m * FFSTR + n] = f;
                    xdst[m * XSTR + n] = __bfloat16_as_ushort(__float2bfloat16(f));
                } else if constexpr (EP == 2) {
                    float f = (featL[m * FFSTR + n] + x) * 0.5f;
                    featL[m * FFSTR + n] = f;
                    xdst[m * XSTR + n] = __bfloat16_as_ushort(__float2bfloat16(f));
                } else {
                    float f = (featL[m * FFSTR + n] + x) * 0.5f;
                    featL[m * FFSTR + n] = f;
                    outFeat[(size_t)(m0 + m) * 192 + n] = f;
                }
            }
        }
    }
}

// ---------------------------------------------------------------------------
// Aggregation: wave's 4 rows interleaved, k-step 8 -> 32 cached bf16 gather
// loads in flight. Tails masked; &8191 keeps speculative loads in-bounds.
// ---------------------------------------------------------------------------
template<int EP>
__device__ __forceinline__ void agg_phase(
    const unsigned short* __restrict__ supR,
    const int* colsL, const int* cntL,
    const float* __restrict__ bias, unsigned short* xdst,
    float* featL, const float* __restrict__ featG,
    float* __restrict__ outFeat,
    int m0, int lane, int wave)
{
    const int base = wave * 4;
    int na[4];
#pragma unroll
    for (int rr = 0; rr < 4; ++rr) na[rr] = cntL[base + rr];
    int nmax = max(max(na[0], na[1]), max(na[2], na[3]));
    float s[4] = {0.f, 0.f, 0.f, 0.f};
    for (int k = 0; k < nmax; k += 8) {
        float v[32];
#pragma unroll
        for (int rr = 0; rr < 4; ++rr) {
            int4 c0 = *reinterpret_cast<const int4*>(colsL + (base + rr) * CAP + k);
            int4 c1 = *reinterpret_cast<const int4*>(colsL + (base + rr) * CAP + k + 4);
            v[rr * 8 + 0] = b2f(supR[((size_t)(c0.x & 8191) << 6) + lane]);
            v[rr * 8 + 1] = b2f(supR[((size_t)(c0.y & 8191) << 6) + lane]);
            v[rr * 8 + 2] = b2f(supR[((size_t)(c0.z & 8191) << 6) + lane]);
            v[rr * 8 + 3] = b2f(supR[((size_t)(c0.w & 8191) << 6) + lane]);
            v[rr * 8 + 4] = b2f(supR[((size_t)(c1.x & 8191) << 6) + lane]);
            v[rr * 8 + 5] = b2f(supR[((size_t)(c1.y & 8191) << 6) + lane]);
            v[rr * 8 + 6] = b2f(supR[((size_t)(c1.z & 8191) << 6) + lane]);
            v[rr * 8 + 7] = b2f(supR[((size_t)(c1.w & 8191) << 6) + lane]);
        }
#pragma unroll
        for (int rr = 0; rr < 4; ++rr) {
#pragma unroll
            for (int j = 0; j < 8; ++j)
                s[rr] += (k + j < na[rr]) ? v[rr * 8 + j] : 0.f;
        }
    }
#pragma unroll
    for (int rr = 0; rr < 4; ++rr) {
        const int lrow = base + rr;
        const int row = m0 + lrow;
        float vv = s[rr] * 0.03125f + bias[lane];
        float x = fmaxf(vv, 0.f);
        if constexpr (EP == 0) {
            xdst[lrow * XSTR + lane] = __bfloat16_as_ushort(__float2bfloat16(x));
        } else if constexpr (EP == 1) {
            float f = (featG[(size_t)row * 256 + lane] + x) * 0.5f;
            featL[lrow * FFSTR + lane] = f;
            xdst[lrow * XSTR + lane] = __bfloat16_as_ushort(__float2bfloat16(f));
        } else if constexpr (EP == 2) {
            float f = (featL[lrow * FFSTR + lane] + x) * 0.5f;
            featL[lrow * FFSTR + lane] = f;
            xdst[lrow * XSTR + lane] = __bfloat16_as_ushort(__float2bfloat16(f));
        } else {
            float f = (featL[lrow * FFSTR + lane] + x) * 0.5f;
            featL[lrow * FFSTR + lane] = f;
            outFeat[(size_t)row * 192 + lane] = f;
        }
    }
}

// ---------------------------------------------------------------------------
// One layer step (layers gc2..gc13). Entering: previous layer's epilogue is
// done and arrive(ph) was issued. Does:
//   hi-mm (K-chunks 2..5, needs only cols 64-191 of x_prev)  [hides barrier]
//   wait(ph)  -> sup_prev visible
//   agg of PREVIOUS layer (completes x_prev cols 0-63), sync
//   lo-mm (K-chunks 0,1) + epilogue of THIS layer -> sup_cur + x_cur
//   arrive(ph+1)
// ---------------------------------------------------------------------------
template<int EPprev, int EPcur>
__device__ __forceinline__ void layer_step(
    int* bar, int ph,
    unsigned short* xsPrev, unsigned short* xsCur,
    const unsigned short* __restrict__ supPrev, unsigned short* __restrict__ supCur,
    const unsigned short* __restrict__ Wt,
    const float* __restrict__ biasPrev, const float* __restrict__ biasCur,
    float* featL, const float* __restrict__ featG, float* __restrict__ outFeat,
    const int* colsL, const int* cntL,
    int m0, int lane, int wave, int quad)
{
    f32x4 acc[3] = {};
    mm_acc<6, 2, 6>(acc, xsPrev, Wt, lane, wave, quad);
    gbar_wait(bar, ph);
    agg_phase<EPprev>(supPrev, colsL, cntL, biasPrev, xsPrev, featL, featG,
                      outFeat, m0, lane, wave);
    __syncthreads();
    mm_acc<6, 0, 2>(acc, xsPrev, Wt, lane, wave, quad);
    mm_epilogue<EPcur>(acc, biasCur, supCur, xsCur, featL, featG, outFeat,
                       m0, lane, wave, quad);
    gbar_arrive(bar, ph + 1);
}

// ---------------------------------------------------------------------------
// Persistent fused kernel. ph1: cooperative weight transform with the
// pipelined adj scan filling the wait. Then split-K layer pipeline: every
// barrier wait is overlapped with the next layer's hi-K MFMAs.
// LDS ~66 KB -> 2 blocks/CU.
// ---------------------------------------------------------------------------
__global__ __launch_bounds__(256, 2) void fused_gcn(
    const float* __restrict__ features,
    const unsigned int* __restrict__ adj,
    const float* __restrict__ W1, const float* __restrict__ Wm,
    unsigned short* __restrict__ Wt1, unsigned short* __restrict__ WtM,
    const float* __restrict__ b1, const float* __restrict__ bm,
    const float* __restrict__ Wout, const float* __restrict__ bout,
    unsigned short* __restrict__ supBase, float* __restrict__ sup3,
    float* __restrict__ out, float* __restrict__ outFeat,
    int* __restrict__ bar)
{
    __shared__ unsigned short xsA[16 * XSTR];
    __shared__ unsigned short xsB[16 * XSTR];
    __shared__ float featL[16 * FFSTR];
    __shared__ int colsL[16 * CAP];
    __shared__ int cntL[16];
    __shared__ __align__(16) unsigned int adjL2[2][4096];   // 2 x 16 KB halves

    const int tid = threadIdx.x;
    const int lane = tid & 63;
    const int wave = tid >> 6;
    const int quad = lane >> 4;
    const int m0 = blockIdx.x * 16;
    int ph = 0;

    // ---- ph1: cooperative weight transform (sc1 stores), arrive
    transform_slice(blockIdx.x * 256 + tid, W1, Wm, Wt1, WtM);
    gbar_arrive(bar, ++ph);

    // ---- pipelined adj scan -> LDS CSR (fills ph1's wait; ~BW-bound)
    if (tid < 16) cntL[tid] = 0;
    {
        auto stage = [&](int hr) {
            const unsigned int* src = adj + ((size_t)(m0 + (hr >> 1)) << 13)
                                          + ((hr & 1) << 12);
            unsigned int* dstb = adjL2[hr & 1];
#pragma unroll
            for (int i = 0; i < 4; ++i) {
                int off = (wave * 4 + i) * 256;          // uints, wave-uniform
                gload_lds16(dstb + off, src + off + lane * 4);
            }
        };
        stage(0);
        for (int hr = 0; hr < 32; ++hr) {
            if (hr < 31) stage(hr + 1);
            __builtin_amdgcn_sched_barrier(0);
            if (hr < 31) asm volatile("s_waitcnt vmcnt(4)" ::: "memory");
            else         asm volatile("s_waitcnt vmcnt(0)" ::: "memory");
            __builtin_amdgcn_sched_barrier(0);
            __syncthreads();
            const int r = hr >> 1;
            const unsigned int* buf = adjL2[hr & 1];
#pragma unroll
            for (int j = 0; j < 4; ++j) {
                int chunk = tid + j * 256;
                uint4 v = *reinterpret_cast<const uint4*>(buf + chunk * 4);
                if ((v.x | v.y | v.z | v.w) == 0u) continue;
                int e0 = ((hr & 1) << 12) + (chunk << 2);
                int loc[4]; int k = 0;
                if (v.x) loc[k++] = e0;
                if (v.y) loc[k++] = e0 + 1;
                if (v.z) loc[k++] = e0 + 2;
                if (v.w) loc[k++] = e0 + 3;
                int pos = atomicAdd(&cntL[r], k);
                for (int jj = 0; jj < k; ++jj)
                    if (pos + jj < CAP) colsL[r * CAP + pos + jj] = loc[jj];
            }
            __syncthreads();
        }
    }
    if (tid < 16) cntL[tid] = cntL[tid] > CAP ? CAP : cntL[tid];
    gbar_wait(bar, ph);                    // weights ready everywhere

    // ---- gc1 (l=1): monolithic KT=8 from features, EP0 -> sup[0], xsA
    {
        s16x8 a8[8];
        load_a_feat(a8, features, m0, lane, quad);
        f32x4 acc[3] = {};
        const short* wb = reinterpret_cast<const short*>(Wt1);
#pragma unroll
        for (int tt = 0; tt < 3; ++tt) {
            const int t = wave * 3 + tt;
            const short* wp = wb + ((size_t)t * 8 * 64 + lane) * 8;
#pragma unroll
            for (int c = 0; c < 8; ++c) {
                s16x8 b = *reinterpret_cast<const s16x8*>(wp + (size_t)c * 512);
                acc[tt] = __builtin_amdgcn_mfma_f32_16x16x32_bf16(a8[c], b, acc[tt], 0, 0, 0);
            }
        }
        mm_epilogue<0>(acc, b1, supBase, xsA, featL, features, outFeat,
                       m0, lane, wave, quad);
    }
    gbar_arrive(bar, ++ph);                // ph=2

    // ---- l=2 (gc2, Wm[0], EP1); agg of gc1 (EP0)
    layer_step<0, 1>(bar, ph, xsA, xsB, supBase, supBase + SUPSZ,
                     WtM, b1, bm, featL, features, outFeat,
                     colsL, cntL, m0, lane, wave, quad);
    ++ph;                                  // ph=3
    // ---- l=3 (gc3, Wm[1], EP0); agg of gc2 (EP1)
    layer_step<1, 0>(bar, ph, xsB, xsA, supBase + SUPSZ, supBase + 2 * SUPSZ,
                     WtM + 36864, bm, bm + 192, featL, features, outFeat,
                     colsL, cntL, m0, lane, wave, quad);
    ++ph;                                  // ph=4
    // ---- l=4 (gc4, Wm[2], EP2); agg of gc3 (EP0)
    layer_step<0, 2>(bar, ph, xsA, xsB, supBase + 2 * SUPSZ, supBase + 3 * SUPSZ,
                     WtM + 2 * 36864, bm + 192, bm + 2 * 192, featL, features,
                     outFeat, colsL, cntL, m0, lane, wave, quad);
    ++ph;                                  // ph=5

    // ---- l=5..12: pairs (odd EP0 after prev EP2; even EP2 after prev EP0)
    for (int p = 1; p <= 4; ++p) {
        const int l = 3 + 2 * p;           // 5,7,9,11
        layer_step<2, 0>(bar, ph, xsB, xsA,
                         supBase + (size_t)(l - 2) * SUPSZ,
                         supBase + (size_t)(l - 1) * SUPSZ,
                         WtM + (size_t)(l - 2) * 36864,
                         bm + (l - 3) * 192, bm + (l - 2) * 192,
                         featL, features, outFeat, colsL, cntL,
                         m0, lane, wave, quad);
        ++ph;
        const int l2 = l + 1;              // 6,8,10,12
        layer_step<0, 2>(bar, ph, xsA, xsB,
                         supBase + (size_t)(l2 - 2) * SUPSZ,
                         supBase + (size_t)(l2 - 1) * SUPSZ,
                         WtM + (size_t)(l2 - 2) * 36864,
                         bm + (l2 - 3) * 192, bm + (l2 - 2) * 192,
                         featL, features, outFeat, colsL, cntL,
                         m0, lane, wave, quad);
        ++ph;
    }                                      // ph=13

    // ---- l=13 (gc13, Wm[11], EP3); agg of gc12 (EP2)
    layer_step<2, 3>(bar, ph, xsB, xsA, supBase + 11 * SUPSZ, supBase + 12 * SUPSZ,
                     WtM + 11 * 36864, bm + 10 * 192, bm + 11 * 192,
                     featL, features, outFeat, colsL, cntL, m0, lane, wave, quad);
    ++ph;                                  // ph=14

    // ---- gc14 matmul, hi part (kk 64..191; featL cols>=64 ready) overlaps wait
    float s3[4][3];
#pragma unroll
    for (int rr = 0; rr < 4; ++rr) { s3[rr][0] = 0.f; s3[rr][1] = 0.f; s3[rr][2] = 0.f; }
#pragma unroll
    for (int rr = 0; rr < 4; ++rr) {
        const int lrow = wave * 4 + rr;
#pragma unroll
        for (int pp = 1; pp < 3; ++pp) {
            int kk = pp * 64 + lane;
            float f = featL[lrow * FFSTR + kk];
            s3[rr][0] += f * Wout[kk * 3 + 0];
            s3[rr][1] += f * Wout[kk * 3 + 1];
            s3[rr][2] += f * Wout[kk * 3 + 2];
        }
    }
    gbar_wait(bar, ph);                    // sup[12] visible
    agg_phase<3>(supBase + (size_t)12 * SUPSZ, colsL, cntL, bm + 11 * 192,
                 xsA, featL, features, outFeat, m0, lane, wave);
    __syncthreads();
#pragma unroll
    for (int rr = 0; rr < 4; ++rr) {
        const int lrow = wave * 4 + rr;
        float f = featL[lrow * FFSTR + lane];
        float s0 = s3[rr][0] + f * Wout[lane * 3 + 0];
        float s1 = s3[rr][1] + f * Wout[lane * 3 + 1];
        float s2 = s3[rr][2] + f * Wout[lane * 3 + 2];
#pragma unroll
        for (int off = 32; off > 0; off >>= 1) {
            s0 += __shfl_down(s0, off);
            s1 += __shfl_down(s1, off);
            s2 += __shfl_down(s2, off);
        }
        if (lane == 0) {
            float* sp = sup3 + (((size_t)(m0 + lrow)) << 2);
            cstoref(sp + 0, s0);
            cstoref(sp + 1, s1);
            cstoref(sp + 2, s2);
        }
    }
    gbar_arrive(bar, ++ph);                // ph=15
    gbar_wait(bar, ph);

    // ---- gc14 aggregation: side_len = 2; 16 threads per row (cached loads)
    {
        const int lrow = tid >> 4;
        const int row = m0 + lrow;
        const int sub = tid & 15;
        int n = cntL[lrow];
        const int* cl = colsL + lrow * CAP;
        float s0 = 0.f, s1 = 0.f;
        for (int k = sub; k < n; k += 16) {
            int j = cl[k];
            s0 += sup3[((size_t)j << 2) + 0];
            s1 += sup3[((size_t)j << 2) + 1];
        }
#pragma unroll
        for (int off = 8; off > 0; off >>= 1) {
            s0 += __shfl_down(s0, off, 16);
            s1 += __shfl_down(s1, off, 16);
        }
        if (sub == 0) {
            float* op = out + (size_t)row * 3;
            op[0] = s0 * 0.03125f + bout[0];
            op[1] = s1 * 0.03125f + bout[1];
            op[2] = sup3[((size_t)row << 2) + 2] + bout[2];
        }
    }
}

extern "C" void kernel_launch(void* const* d_in, const int* in_sizes, int n_in,
                              void* d_out, int out_size, void* d_ws, size_t ws_size,
                              hipStream_t stream) {
    const float* features = (const float*)d_in[0];
    const unsigned int* adj = (const unsigned int*)d_in[1];
    const float* W1 = (const float*)d_in[2];
    const float* b1 = (const float*)d_in[3];
    const float* Wm = (const float*)d_in[4];
    const float* bm = (const float*)d_in[5];
    const float* Wo = (const float*)d_in[6];
    const float* bo = (const float*)d_in[7];
    float* out = (float*)d_out;
    float* outFeat = out + (size_t)N_NODES * 3;

    char* w = (char*)d_ws;
    int* bar = (int*)(w);                                     // 128 KB flags
    unsigned short* supBase = (unsigned short*)(w + 131072);  // 13 x 1 MB -> 13,762,560
    float* sup3 = (float*)(w + 13762560);                     // 128 KB -> 13,893,632
    unsigned short* Wt1 = (unsigned short*)(w + 13893632);    // 96 KB -> 13,991,936
    unsigned short* WtM = (unsigned short*)(w + 13991936);    // 864 KB -> 14,876,672

    hipMemsetAsync(bar, 0, 131072, stream);

    fused_gcn<<<NBLK, 256, 0, stream>>>(features, adj, W1, Wm, Wt1, WtM, b1, bm,
                                        Wo, bo, supBase, sup3, out, outFeat, bar);

    (void)in_sizes; (void)n_in; (void)out_size; (void)ws_size;
}